// Round 2
// baseline (140.432 us; speedup 1.0000x reference)
//
#include <hip/hip_runtime.h>

// WaveletProcessor: 4x [Conv1d(64,64,k) -> ReLU -> Conv1d(64,64,1)], softmax-weighted sum.
// Device buffers are float32 (reference dtype). Compute in bf16 MFMA, fp32 accum.
// B=32, L=8192, C=64; k = {3,3,5,9}, pad = {1,1,2,4}.

constexpr int Bn = 32, Ln = 8192, Cn = 64;
constexpr int NT = 256;          // length-tile per workgroup
constexpr int HALO = 4;          // max pad
constexpr int XROWS = NT + 2 * HALO;   // 264
constexpr int RS = 72;           // LDS row stride in ushorts (144B -> 2-way bank alias only)

using bf16x8 = __attribute__((ext_vector_type(8))) __bf16;
using f32x4  = __attribute__((ext_vector_type(4))) float;
using u16x8  = __attribute__((ext_vector_type(8))) unsigned short;
using u16x4  = __attribute__((ext_vector_type(4))) unsigned short;

struct Ptrs {
    const float* x;
    const float* rw;
    const float* w1[4];
    const float* b1[4];
    const float* w2[4];
    const float* b2[4];
};

__device__ __forceinline__ unsigned short f2bf(float f) {
    unsigned u = __builtin_bit_cast(unsigned, f);
    u += 0x7fffu + ((u >> 16) & 1u);   // RNE (values are finite/normal here)
    return (unsigned short)(u >> 16);
}

// ---------------- prep: softmax + weight fragment pre-transposition ----------------
// d_ws layout: [0..3] float softmax w; [4..67] float fused bias (sum_i w_i*b2_i);
// at byte 512: bf16 fragment blocks, 512 elems (1KB) each:
//   F1: branch bases (blocks) {0,24,48,88}, block idx within branch = dk*8 + ks*4 + mt
//   F2: base block 160 + br*8, block idx = ks*4 + mt   (W2 pre-scaled by w[br])
// Within a block: lane*8 + j ; A[m=co][k=ci]: co = mt*16 + (lane&15), ci = ks*32 + (lane>>4)*8 + j.
__global__ void prep_kernel(Ptrs p, unsigned short* __restrict__ frag, float* __restrict__ hdr) {
    int tid = threadIdx.x;
    float v0 = p.rw[0], v1 = p.rw[1], v2 = p.rw[2], v3 = p.rw[3];
    float m = fmaxf(fmaxf(v0, v1), fmaxf(v2, v3));
    float e0 = expf(v0 - m), e1 = expf(v1 - m), e2 = expf(v2 - m), e3 = expf(v3 - m);
    float s = e0 + e1 + e2 + e3;
    float w[4] = {e0 / s, e1 / s, e2 / s, e3 / s};

    if (blockIdx.x == 0) {
        if (tid < 4) hdr[tid] = w[tid];
        if (tid < 64) {
            float fb = 0.f;
            #pragma unroll
            for (int i = 0; i < 4; i++) fb += w[i] * p.b2[i][tid];
            hdr[4 + tid] = fb;
        }
    }

    const int kk[4] = {3, 3, 5, 9};
    const int f1blocks[4] = {24, 24, 40, 72};   // k*8 blocks per branch

    for (int idx = blockIdx.x * blockDim.x + tid; idx < 192 * 512; idx += gridDim.x * blockDim.x) {
        int blk = idx >> 9;
        int e = idx & 511;
        int lane = e >> 3, j = e & 7;
        int col = lane & 15, kg = lane >> 4;
        unsigned short val;
        if (blk < 160) {
            int br = 0, rem = blk;
            while (rem >= f1blocks[br]) { rem -= f1blocks[br]; br++; }
            int dk = rem >> 3, ks = (rem >> 2) & 1, mt = rem & 3;
            int co = mt * 16 + col;
            int ci = ks * 32 + kg * 8 + j;
            val = f2bf(p.w1[br][(co * 64 + ci) * kk[br] + dk]);
        } else {
            int rem = blk - 160;
            int br = rem >> 3, ks = (rem >> 2) & 1, mt = rem & 3;
            int co = mt * 16 + col;
            int ci = ks * 32 + kg * 8 + j;
            val = f2bf(w[br] * p.w2[br][co * 64 + ci]);
        }
        frag[idx] = val;
    }
}

// ---------------- main kernel ----------------
template <int KK, int PP>
__device__ __forceinline__ void do_branch(const unsigned short* __restrict__ frag1,
                                          const unsigned short* __restrict__ frag2,
                                          const float* __restrict__ b1,
                                          unsigned short* xs, unsigned short* hs,
                                          int lane, int wl0, f32x4 (&fused)[4][4]) {
    int col = lane & 15, kg = lane >> 4;

    // conv1 accumulators initialized to b1[co]
    f32x4 acc[4][4];
    #pragma unroll
    for (int mt = 0; mt < 4; mt++) {
        f32x4 bi;
        #pragma unroll
        for (int r = 0; r < 4; r++) bi[r] = b1[mt * 16 + kg * 4 + r];
        #pragma unroll
        for (int nt = 0; nt < 4; nt++) acc[mt][nt] = bi;
    }

    #pragma unroll
    for (int dk = 0; dk < KK; dk++) {
        #pragma unroll
        for (int ks = 0; ks < 2; ks++) {
            bf16x8 bfr[4];
            #pragma unroll
            for (int nt = 0; nt < 4; nt++) {
                int row = wl0 + nt * 16 + col + (HALO - PP) + dk;
                bfr[nt] = __builtin_bit_cast(bf16x8, *(const u16x8*)&xs[row * RS + ks * 32 + kg * 8]);
            }
            const unsigned short* fp = frag1 + (size_t)(dk * 8 + ks * 4) * 512 + lane * 8;
            #pragma unroll
            for (int mt = 0; mt < 4; mt++) {
                bf16x8 afr = __builtin_bit_cast(bf16x8, *(const u16x8*)(fp + (size_t)mt * 512));
                #pragma unroll
                for (int nt = 0; nt < 4; nt++)
                    acc[mt][nt] = __builtin_amdgcn_mfma_f32_16x16x32_bf16(afr, bfr[nt], acc[mt][nt], 0, 0, 0);
            }
        }
    }

    __syncthreads();   // previous branch's conv2 reads of hs are done
    // ReLU + pack to LDS H (bf16). D layout: col = lane&15 (l), row = (lane>>4)*4 + r (co).
    #pragma unroll
    for (int mt = 0; mt < 4; mt++) {
        #pragma unroll
        for (int nt = 0; nt < 4; nt++) {
            u16x4 hv;
            #pragma unroll
            for (int r = 0; r < 4; r++) hv[r] = f2bf(fmaxf(acc[mt][nt][r], 0.f));
            int row = wl0 + nt * 16 + col;
            *(u16x4*)&hs[row * RS + mt * 16 + kg * 4] = hv;
        }
    }
    __syncthreads();   // hs ready

    // conv2 (1x1), W2 pre-scaled by softmax weight; accumulate into fused
    #pragma unroll
    for (int ks = 0; ks < 2; ks++) {
        bf16x8 bfr[4];
        #pragma unroll
        for (int nt = 0; nt < 4; nt++) {
            int row = wl0 + nt * 16 + col;
            bfr[nt] = __builtin_bit_cast(bf16x8, *(const u16x8*)&hs[row * RS + ks * 32 + kg * 8]);
        }
        const unsigned short* fp = frag2 + (size_t)(ks * 4) * 512 + lane * 8;
        #pragma unroll
        for (int mt = 0; mt < 4; mt++) {
            bf16x8 afr = __builtin_bit_cast(bf16x8, *(const u16x8*)(fp + (size_t)mt * 512));
            #pragma unroll
            for (int nt = 0; nt < 4; nt++)
                fused[mt][nt] = __builtin_amdgcn_mfma_f32_16x16x32_bf16(afr, bfr[nt], fused[mt][nt], 0, 0, 0);
        }
    }
}

__global__ __launch_bounds__(256, 2) void wavelet_main(Ptrs p,
                                                       const unsigned short* __restrict__ frag,
                                                       const float* __restrict__ hdr,
                                                       float* __restrict__ out) {
    __shared__ unsigned short xs[XROWS * RS];   // 38016 B
    __shared__ unsigned short hs[NT * RS];      // 36864 B

    int tid = threadIdx.x;
    int b = blockIdx.x >> 5;           // 32 tiles per batch
    int t0 = (blockIdx.x & 31) * NT;

    // stage x tile (+halo) into LDS as bf16, zero-padded at batch edges
    {
        int c0 = (tid & 7) * 8;
        int rbase = tid >> 3;
        #pragma unroll
        for (int it = 0; it < 9; it++) {
            int rr = it * 32 + rbase;
            if (rr < XROWS) {
                int l = t0 + rr - HALO;
                u16x8 v = {0, 0, 0, 0, 0, 0, 0, 0};
                if (l >= 0 && l < Ln) {
                    const float* src = &p.x[((size_t)b * Ln + l) * 64 + c0];
                    f32x4 a0 = *(const f32x4*)src;
                    f32x4 a1 = *(const f32x4*)(src + 4);
                    #pragma unroll
                    for (int r = 0; r < 4; r++) { v[r] = f2bf(a0[r]); v[4 + r] = f2bf(a1[r]); }
                }
                *(u16x8*)&xs[rr * RS + c0] = v;
            }
        }
    }

    int lane = tid & 63;
    int wl0 = (tid >> 6) * 64;   // each wave owns a 64-wide L-chunk
    int kg = lane >> 4;

    // fused accumulator init = sum_i w_i * b2_i[co]
    f32x4 fused[4][4];
    #pragma unroll
    for (int mt = 0; mt < 4; mt++) {
        f32x4 fi;
        #pragma unroll
        for (int r = 0; r < 4; r++) fi[r] = hdr[4 + mt * 16 + kg * 4 + r];
        #pragma unroll
        for (int nt = 0; nt < 4; nt++) fused[mt][nt] = fi;
    }

    __syncthreads();   // xs ready

    do_branch<3, 1>(frag + (size_t)0 * 512,  frag + (size_t)(160 + 0)  * 512, p.b1[0], xs, hs, lane, wl0, fused);
    do_branch<3, 1>(frag + (size_t)24 * 512, frag + (size_t)(160 + 8)  * 512, p.b1[1], xs, hs, lane, wl0, fused);
    do_branch<5, 2>(frag + (size_t)48 * 512, frag + (size_t)(160 + 16) * 512, p.b1[2], xs, hs, lane, wl0, fused);
    do_branch<9, 4>(frag + (size_t)88 * 512, frag + (size_t)(160 + 24) * 512, p.b1[3], xs, hs, lane, wl0, fused);

    // write output: out[b][l][c] = fused[c][l], fp32, channel-contiguous float4
    int col = lane & 15;
    #pragma unroll
    for (int mt = 0; mt < 4; mt++) {
        #pragma unroll
        for (int nt = 0; nt < 4; nt++) {
            int l = t0 + wl0 + nt * 16 + col;
            *(f32x4*)&out[((size_t)b * Ln + l) * 64 + mt * 16 + kg * 4] = fused[mt][nt];
        }
    }
}

extern "C" void kernel_launch(void* const* d_in, const int* in_sizes, int n_in,
                              void* d_out, int out_size, void* d_ws, size_t ws_size,
                              hipStream_t stream) {
    Ptrs p;
    p.x  = (const float*)d_in[0];
    p.rw = (const float*)d_in[1];
    for (int i = 0; i < 4; i++) {
        p.w1[i] = (const float*)d_in[2 + 4 * i];
        p.b1[i] = (const float*)d_in[3 + 4 * i];
        p.w2[i] = (const float*)d_in[4 + 4 * i];
        p.b2[i] = (const float*)d_in[5 + 4 * i];
    }
    float* hdr = (float*)d_ws;
    unsigned short* frag = (unsigned short*)((char*)d_ws + 512);

    hipLaunchKernelGGL(prep_kernel, dim3(96), dim3(256), 0, stream, p, frag, hdr);
    hipLaunchKernelGGL(wavelet_main, dim3(Bn * (Ln / NT)), dim3(256), 0, stream, p, frag, hdr,
                       (float*)d_out);
}

// Round 3
// 135.866 us; speedup vs baseline: 1.0336x; 1.0336x over previous
//
#include <hip/hip_runtime.h>

// WaveletProcessor: 4x [Conv1d(64,64,k) -> ReLU -> Conv1d(64,64,1)], softmax-weighted sum.
// Device buffers are float32. Compute: bf16 MFMA, fp32 accum.
// Round 3: conv2 consumes ReLU(conv1) directly from registers via 16x16x16 MFMA
// (conv1 D-layout == conv2 B-layout), removing the H LDS buffer and all inter-branch
// barriers. NT=128, nt=2 per wave, target 4 waves/SIMD.

constexpr int Bn = 32, Ln = 8192;
constexpr int NT = 128;          // length-tile per workgroup (4 waves x 32)
constexpr int HALO = 4;          // max pad
constexpr int XROWS = NT + 2 * HALO;   // 136
constexpr int RS = 72;           // LDS row stride in ushorts (144B -> 2-way alias, free)

using bf16x8 = __attribute__((ext_vector_type(8))) __bf16;
using f32x4  = __attribute__((ext_vector_type(4))) float;
using u16x8  = __attribute__((ext_vector_type(8))) unsigned short;
using u16x4  = __attribute__((ext_vector_type(4))) unsigned short;
using s16x4  = __attribute__((ext_vector_type(4))) short;

struct Ptrs {
    const float* x;
    const float* rw;
    const float* w1[4];
    const float* b1[4];
    const float* w2[4];
    const float* b2[4];
};

__device__ __forceinline__ unsigned short f2bf(float f) {
    unsigned u = __builtin_bit_cast(unsigned, f);
    u += 0x7fffu + ((u >> 16) & 1u);   // RNE
    return (unsigned short)(u >> 16);
}

#if defined(__has_builtin)
#  if __has_builtin(__builtin_amdgcn_mfma_f32_16x16x16bf16_1k)
#    define HAVE_MFMA16 1
#  endif
#endif

__device__ __forceinline__ void mfma16(f32x4& c, u16x4 a, u16x4 b) {
#ifdef HAVE_MFMA16
    c = __builtin_amdgcn_mfma_f32_16x16x16bf16_1k(
            __builtin_bit_cast(s16x4, a), __builtin_bit_cast(s16x4, b), c, 0, 0, 0);
#else
    asm("v_mfma_f32_16x16x16_bf16 %0, %1, %2, %0" : "+v"(c) : "v"(a), "v"(b));
#endif
}

// ---------------- prep: softmax + weight fragment pre-transposition ----------------
// d_ws layout: [0..3] float softmax w; [4..67] float fused bias (sum_i w_i*b2_i);
// at byte 512, bf16 fragments:
//   F1 (conv1 A, 16x16x32): 160 blocks x 512 elems; branch bases {0,24,48,88} blocks,
//     block = dk*8 + ks*4 + mt; elem = lane*8+j; co=mt*16+(lane&15), ci=ks*32+(lane>>4)*8+j.
//   F2 (conv2 A, 16x16x16): base elem 81920; branch br at +br*4096; frag (kb,mt) at
//     +(kb*4+mt)*256; elem = lane*4+j; co2=mt*16+(lane&15), ci=kb*16+(lane>>4)*4+j;
//     value pre-scaled by softmax w[br].
__global__ void prep_kernel(Ptrs p, unsigned short* __restrict__ frag, float* __restrict__ hdr) {
    int tid = threadIdx.x;
    float v0 = p.rw[0], v1 = p.rw[1], v2 = p.rw[2], v3 = p.rw[3];
    float m = fmaxf(fmaxf(v0, v1), fmaxf(v2, v3));
    float e0 = expf(v0 - m), e1 = expf(v1 - m), e2 = expf(v2 - m), e3 = expf(v3 - m);
    float s = e0 + e1 + e2 + e3;
    float w[4] = {e0 / s, e1 / s, e2 / s, e3 / s};

    if (blockIdx.x == 0) {
        if (tid < 4) hdr[tid] = w[tid];
        if (tid < 64) {
            float fb = 0.f;
            #pragma unroll
            for (int i = 0; i < 4; i++) fb += w[i] * p.b2[i][tid];
            hdr[4 + tid] = fb;
        }
    }

    const int kk[4] = {3, 3, 5, 9};
    const int f1blocks[4] = {24, 24, 40, 72};

    for (int idx = blockIdx.x * blockDim.x + tid; idx < 81920 + 16384; idx += gridDim.x * blockDim.x) {
        unsigned short val;
        if (idx < 81920) {
            int blk = idx >> 9;
            int e = idx & 511;
            int lane = e >> 3, j = e & 7;
            int br = 0, rem = blk;
            while (rem >= f1blocks[br]) { rem -= f1blocks[br]; br++; }
            int dk = rem >> 3, ks = (rem >> 2) & 1, mt = rem & 3;
            int co = mt * 16 + (lane & 15);
            int ci = ks * 32 + (lane >> 4) * 8 + j;
            val = f2bf(p.w1[br][(co * 64 + ci) * kk[br] + dk]);
        } else {
            int e2 = idx - 81920;
            int br = e2 >> 12;
            int fi = (e2 >> 8) & 15;       // kb*4 + mt
            int kb = fi >> 2, mt = fi & 3;
            int e = e2 & 255;
            int lane = e >> 2, j = e & 3;
            int co = mt * 16 + (lane & 15);
            int ci = kb * 16 + (lane >> 4) * 4 + j;
            val = f2bf(w[br] * p.w2[br][co * 64 + ci]);
        }
        frag[idx] = val;
    }
}

// ---------------- main kernel ----------------
template <int KK, int PP>
__device__ __forceinline__ void do_branch(const unsigned short* __restrict__ frag1,
                                          const unsigned short* __restrict__ frag2,
                                          const float* __restrict__ b1,
                                          const unsigned short* xs,
                                          int lane, int wl0, f32x4 (&fused)[4][2]) {
    int col = lane & 15, kg = lane >> 4;

    // conv1 accumulators initialized to b1[co]
    f32x4 acc[4][2];
    #pragma unroll
    for (int mt = 0; mt < 4; mt++) {
        f32x4 bi;
        #pragma unroll
        for (int r = 0; r < 4; r++) bi[r] = b1[mt * 16 + kg * 4 + r];
        acc[mt][0] = bi; acc[mt][1] = bi;
    }

    #pragma unroll
    for (int dk = 0; dk < KK; dk++) {
        #pragma unroll
        for (int ks = 0; ks < 2; ks++) {
            bf16x8 bfr[2];
            #pragma unroll
            for (int nt = 0; nt < 2; nt++) {
                int row = wl0 + nt * 16 + col + (HALO - PP) + dk;
                bfr[nt] = __builtin_bit_cast(bf16x8, *(const u16x8*)&xs[row * RS + ks * 32 + kg * 8]);
            }
            const unsigned short* fp = frag1 + (size_t)(dk * 8 + ks * 4) * 512 + lane * 8;
            #pragma unroll
            for (int mt = 0; mt < 4; mt++) {
                bf16x8 afr = __builtin_bit_cast(bf16x8, *(const u16x8*)(fp + (size_t)mt * 512));
                #pragma unroll
                for (int nt = 0; nt < 2; nt++)
                    acc[mt][nt] = __builtin_amdgcn_mfma_f32_16x16x32_bf16(afr, bfr[nt], acc[mt][nt], 0, 0, 0);
            }
        }
    }

    // conv2 (1x1) straight from registers: ReLU(acc) repacked in-lane is the
    // 16x16x16 B-fragment (conv1 D row co == conv2 k ci; col l unchanged).
    #pragma unroll
    for (int kb = 0; kb < 4; kb++) {
        u16x4 hb[2];
        #pragma unroll
        for (int nt = 0; nt < 2; nt++) {
            u16x4 h;
            #pragma unroll
            for (int r = 0; r < 4; r++) h[r] = f2bf(fmaxf(acc[kb][nt][r], 0.f));
            hb[nt] = h;
        }
        const unsigned short* fp2 = frag2 + (size_t)kb * 4 * 256 + lane * 4;
        #pragma unroll
        for (int mt = 0; mt < 4; mt++) {
            u16x4 afr = *(const u16x4*)(fp2 + (size_t)mt * 256);
            #pragma unroll
            for (int nt = 0; nt < 2; nt++)
                mfma16(fused[mt][nt], afr, hb[nt]);
        }
    }
}

__global__ __launch_bounds__(256, 4) void wavelet_main(Ptrs p,
                                                       const unsigned short* __restrict__ frag,
                                                       const float* __restrict__ hdr,
                                                       float* __restrict__ out) {
    __shared__ unsigned short xs[XROWS * RS];   // 19584 B

    int tid = threadIdx.x;
    int b = blockIdx.x >> 6;           // 64 tiles per batch
    int t0 = (blockIdx.x & 63) * NT;

    // stage x tile (+halo) into LDS as bf16, zero-padded at batch edges
    {
        int c0 = (tid & 7) * 8;
        int rbase = tid >> 3;          // 0..31
        #pragma unroll
        for (int it = 0; it < 5; it++) {
            int rr = it * 32 + rbase;
            if (rr < XROWS) {
                int l = t0 + rr - HALO;
                u16x8 v = {0, 0, 0, 0, 0, 0, 0, 0};
                if (l >= 0 && l < Ln) {
                    const float* src = &p.x[((size_t)b * Ln + l) * 64 + c0];
                    f32x4 a0 = *(const f32x4*)src;
                    f32x4 a1 = *(const f32x4*)(src + 4);
                    #pragma unroll
                    for (int r = 0; r < 4; r++) { v[r] = f2bf(a0[r]); v[4 + r] = f2bf(a1[r]); }
                }
                *(u16x8*)&xs[rr * RS + c0] = v;
            }
        }
    }

    int lane = tid & 63;
    int wl0 = (tid >> 6) * 32;   // each wave owns a 32-wide L-chunk
    int kg = lane >> 4;

    // fused accumulator init = sum_i w_i * b2_i[co]
    f32x4 fused[4][2];
    #pragma unroll
    for (int mt = 0; mt < 4; mt++) {
        f32x4 fi;
        #pragma unroll
        for (int r = 0; r < 4; r++) fi[r] = hdr[4 + mt * 16 + kg * 4 + r];
        fused[mt][0] = fi; fused[mt][1] = fi;
    }

    __syncthreads();   // xs ready — the only barrier

    do_branch<3, 1>(frag + (size_t)0 * 512,  frag + 81920 + (size_t)0 * 4096, p.b1[0], xs, lane, wl0, fused);
    do_branch<3, 1>(frag + (size_t)24 * 512, frag + 81920 + (size_t)1 * 4096, p.b1[1], xs, lane, wl0, fused);
    do_branch<5, 2>(frag + (size_t)48 * 512, frag + 81920 + (size_t)2 * 4096, p.b1[2], xs, lane, wl0, fused);
    do_branch<9, 4>(frag + (size_t)88 * 512, frag + 81920 + (size_t)3 * 4096, p.b1[3], xs, lane, wl0, fused);

#ifndef HAVE_MFMA16
    asm volatile("s_nop 7\ns_nop 7");   // MFMA->VALU hazard guard for asm path
#endif

    // write output: out[b][l][c] = fused[c][l], fp32, channel-contiguous float4
    int col = lane & 15;
    #pragma unroll
    for (int mt = 0; mt < 4; mt++) {
        #pragma unroll
        for (int nt = 0; nt < 2; nt++) {
            int l = t0 + wl0 + nt * 16 + col;
            *(f32x4*)&out[((size_t)b * Ln + l) * 64 + mt * 16 + kg * 4] = fused[mt][nt];
        }
    }
}

extern "C" void kernel_launch(void* const* d_in, const int* in_sizes, int n_in,
                              void* d_out, int out_size, void* d_ws, size_t ws_size,
                              hipStream_t stream) {
    Ptrs p;
    p.x  = (const float*)d_in[0];
    p.rw = (const float*)d_in[1];
    for (int i = 0; i < 4; i++) {
        p.w1[i] = (const float*)d_in[2 + 4 * i];
        p.b1[i] = (const float*)d_in[3 + 4 * i];
        p.w2[i] = (const float*)d_in[4 + 4 * i];
        p.b2[i] = (const float*)d_in[5 + 4 * i];
    }
    float* hdr = (float*)d_ws;
    unsigned short* frag = (unsigned short*)((char*)d_ws + 512);

    hipLaunchKernelGGL(prep_kernel, dim3(96), dim3(256), 0, stream, p, frag, hdr);
    hipLaunchKernelGGL(wavelet_main, dim3(Bn * (Ln / NT)), dim3(256), 0, stream, p, frag, hdr,
                       (float*)d_out);
}

// Round 4
// 85.688 us; speedup vs baseline: 1.6389x; 1.5856x over previous
//
#include <hip/hip_runtime.h>

// WaveletProcessor: 4x [Conv1d(64,64,k) -> ReLU -> Conv1d(64,64,1)], softmax-weighted sum.
// Device buffers are float32. Compute: bf16 MFMA, fp32 accum.
// Round 4: nt=4 (64 length-cols per wave, NT=256/block). 16 MFMAs per (dk,ks) phase
// gives the scheduler ~310 cyc of MFMA issue to hide frag/LDS load latency; weight
// fragment traffic per output halves. conv2 still consumed straight from registers
// (conv1 D-layout == 16x16x16 B-layout). One barrier per block. 2 waves/SIMD target.

constexpr int Bn = 32, Ln = 8192;
constexpr int NT = 256;          // length-tile per workgroup (4 waves x 64)
constexpr int HALO = 4;          // max pad
constexpr int XROWS = NT + 2 * HALO;   // 264
constexpr int RS = 72;           // LDS row stride in ushorts (144B -> 2-way alias, free)

using bf16x8 = __attribute__((ext_vector_type(8))) __bf16;
using f32x4  = __attribute__((ext_vector_type(4))) float;
using u16x8  = __attribute__((ext_vector_type(8))) unsigned short;
using u16x4  = __attribute__((ext_vector_type(4))) unsigned short;
using s16x4  = __attribute__((ext_vector_type(4))) short;

struct Ptrs {
    const float* x;
    const float* rw;
    const float* w1[4];
    const float* b1[4];
    const float* w2[4];
    const float* b2[4];
};

__device__ __forceinline__ unsigned short f2bf(float f) {
    __bf16 h = (__bf16)f;                       // native cvt (v_cvt_pk_bf16_f32), RNE
    return __builtin_bit_cast(unsigned short, h);
}

#if defined(__has_builtin)
#  if __has_builtin(__builtin_amdgcn_mfma_f32_16x16x16bf16_1k)
#    define HAVE_MFMA16 1
#  endif
#endif

__device__ __forceinline__ void mfma16(f32x4& c, u16x4 a, u16x4 b) {
#ifdef HAVE_MFMA16
    c = __builtin_amdgcn_mfma_f32_16x16x16bf16_1k(
            __builtin_bit_cast(s16x4, a), __builtin_bit_cast(s16x4, b), c, 0, 0, 0);
#else
    asm("v_mfma_f32_16x16x16_bf16 %0, %1, %2, %0" : "+v"(c) : "v"(a), "v"(b));
#endif
}

// ---------------- prep: softmax + weight fragment pre-transposition ----------------
// d_ws layout: [0..3] float softmax w; [4..67] float fused bias (sum_i w_i*b2_i);
// at byte 512, bf16 fragments:
//   F1 (conv1 A, 16x16x32): 160 blocks x 512 elems; branch bases {0,24,48,88} blocks,
//     block = dk*8 + ks*4 + mt; elem = lane*8+j; co=mt*16+(lane&15), ci=ks*32+(lane>>4)*8+j.
//   F2 (conv2 A, 16x16x16): base elem 81920; branch br at +br*4096; frag (kb,mt) at
//     +(kb*4+mt)*256; elem = lane*4+j; co2=mt*16+(lane&15), ci=kb*16+(lane>>4)*4+j;
//     value pre-scaled by softmax w[br].
__global__ void prep_kernel(Ptrs p, unsigned short* __restrict__ frag, float* __restrict__ hdr) {
    int tid = threadIdx.x;
    float v0 = p.rw[0], v1 = p.rw[1], v2 = p.rw[2], v3 = p.rw[3];
    float m = fmaxf(fmaxf(v0, v1), fmaxf(v2, v3));
    float e0 = expf(v0 - m), e1 = expf(v1 - m), e2 = expf(v2 - m), e3 = expf(v3 - m);
    float s = e0 + e1 + e2 + e3;
    float w[4] = {e0 / s, e1 / s, e2 / s, e3 / s};

    if (blockIdx.x == 0) {
        if (tid < 4) hdr[tid] = w[tid];
        if (tid < 64) {
            float fb = 0.f;
            #pragma unroll
            for (int i = 0; i < 4; i++) fb += w[i] * p.b2[i][tid];
            hdr[4 + tid] = fb;
        }
    }

    const int kk[4] = {3, 3, 5, 9};
    const int f1blocks[4] = {24, 24, 40, 72};

    for (int idx = blockIdx.x * blockDim.x + tid; idx < 81920 + 16384; idx += gridDim.x * blockDim.x) {
        unsigned short val;
        if (idx < 81920) {
            int blk = idx >> 9;
            int e = idx & 511;
            int lane = e >> 3, j = e & 7;
            int br = 0, rem = blk;
            while (rem >= f1blocks[br]) { rem -= f1blocks[br]; br++; }
            int dk = rem >> 3, ks = (rem >> 2) & 1, mt = rem & 3;
            int co = mt * 16 + (lane & 15);
            int ci = ks * 32 + (lane >> 4) * 8 + j;
            val = f2bf(p.w1[br][(co * 64 + ci) * kk[br] + dk]);
        } else {
            int e2 = idx - 81920;
            int br = e2 >> 12;
            int fi = (e2 >> 8) & 15;       // kb*4 + mt
            int kb = fi >> 2, mt = fi & 3;
            int e = e2 & 255;
            int lane = e >> 2, j = e & 3;
            int co = mt * 16 + (lane & 15);
            int ci = kb * 16 + (lane >> 4) * 4 + j;
            val = f2bf(w[br] * p.w2[br][co * 64 + ci]);
        }
        frag[idx] = val;
    }
}

// ---------------- main kernel ----------------
template <int KK, int PP>
__device__ __forceinline__ void do_branch(const unsigned short* __restrict__ frag1,
                                          const unsigned short* __restrict__ frag2,
                                          const float* __restrict__ b1,
                                          const unsigned short* xs,
                                          int lane, int wl0, f32x4 (&fused)[4][4]) {
    int col = lane & 15, kg = lane >> 4;

    // conv1 accumulators initialized to b1[co]
    f32x4 acc[4][4];
    #pragma unroll
    for (int mt = 0; mt < 4; mt++) {
        f32x4 bi;
        #pragma unroll
        for (int r = 0; r < 4; r++) bi[r] = b1[mt * 16 + kg * 4 + r];
        #pragma unroll
        for (int nt = 0; nt < 4; nt++) acc[mt][nt] = bi;
    }

    #pragma unroll
    for (int dk = 0; dk < KK; dk++) {
        #pragma unroll
        for (int ks = 0; ks < 2; ks++) {
            bf16x8 bfr[4];
            #pragma unroll
            for (int nt = 0; nt < 4; nt++) {
                int row = wl0 + nt * 16 + col + (HALO - PP) + dk;
                bfr[nt] = __builtin_bit_cast(bf16x8, *(const u16x8*)&xs[row * RS + ks * 32 + kg * 8]);
            }
            const unsigned short* fp = frag1 + (size_t)(dk * 8 + ks * 4) * 512 + lane * 8;
            #pragma unroll
            for (int mt = 0; mt < 4; mt++) {
                bf16x8 afr = __builtin_bit_cast(bf16x8, *(const u16x8*)(fp + (size_t)mt * 512));
                #pragma unroll
                for (int nt = 0; nt < 4; nt++)
                    acc[mt][nt] = __builtin_amdgcn_mfma_f32_16x16x32_bf16(afr, bfr[nt], acc[mt][nt], 0, 0, 0);
            }
        }
    }

    // conv2 (1x1) straight from registers: ReLU(acc) repacked in-lane is the
    // 16x16x16 B-fragment (conv1 D row co == conv2 k ci; col l unchanged).
    #pragma unroll
    for (int kb = 0; kb < 4; kb++) {
        u16x4 hb[4];
        #pragma unroll
        for (int nt = 0; nt < 4; nt++) {
            u16x4 h;
            #pragma unroll
            for (int r = 0; r < 4; r++) h[r] = f2bf(fmaxf(acc[kb][nt][r], 0.f));
            hb[nt] = h;
        }
        const unsigned short* fp2 = frag2 + (size_t)kb * 4 * 256 + lane * 4;
        #pragma unroll
        for (int mt = 0; mt < 4; mt++) {
            u16x4 afr = *(const u16x4*)(fp2 + (size_t)mt * 256);
            #pragma unroll
            for (int nt = 0; nt < 4; nt++)
                mfma16(fused[mt][nt], afr, hb[nt]);
        }
    }
}

__global__ __launch_bounds__(256, 2) void wavelet_main(Ptrs p,
                                                       const unsigned short* __restrict__ frag,
                                                       const float* __restrict__ hdr,
                                                       float* __restrict__ out) {
    __shared__ unsigned short xs[XROWS * RS];   // 38016 B

    int tid = threadIdx.x;
    int b = blockIdx.x >> 5;           // 32 tiles per batch
    int t0 = (blockIdx.x & 31) * NT;

    // stage x tile (+halo) into LDS as bf16, zero-padded at batch edges
    {
        int c0 = (tid & 7) * 8;
        int rbase = tid >> 3;          // 0..31
        #pragma unroll
        for (int it = 0; it < 9; it++) {
            int rr = it * 32 + rbase;
            if (rr < XROWS) {
                int l = t0 + rr - HALO;
                u16x8 v = {0, 0, 0, 0, 0, 0, 0, 0};
                if (l >= 0 && l < Ln) {
                    const float* src = &p.x[((size_t)b * Ln + l) * 64 + c0];
                    f32x4 a0 = *(const f32x4*)src;
                    f32x4 a1 = *(const f32x4*)(src + 4);
                    #pragma unroll
                    for (int r = 0; r < 4; r++) { v[r] = f2bf(a0[r]); v[4 + r] = f2bf(a1[r]); }
                }
                *(u16x8*)&xs[rr * RS + c0] = v;
            }
        }
    }

    int lane = tid & 63;
    int wl0 = (tid >> 6) * 64;   // each wave owns a 64-wide L-chunk
    int kg = lane >> 4;

    // fused accumulator init = sum_i w_i * b2_i[co]
    f32x4 fused[4][4];
    #pragma unroll
    for (int mt = 0; mt < 4; mt++) {
        f32x4 fi;
        #pragma unroll
        for (int r = 0; r < 4; r++) fi[r] = hdr[4 + mt * 16 + kg * 4 + r];
        #pragma unroll
        for (int nt = 0; nt < 4; nt++) fused[mt][nt] = fi;
    }

    __syncthreads();   // xs ready — the only barrier

    do_branch<3, 1>(frag + (size_t)0 * 512,  frag + 81920 + (size_t)0 * 4096, p.b1[0], xs, lane, wl0, fused);
    do_branch<3, 1>(frag + (size_t)24 * 512, frag + 81920 + (size_t)1 * 4096, p.b1[1], xs, lane, wl0, fused);
    do_branch<5, 2>(frag + (size_t)48 * 512, frag + 81920 + (size_t)2 * 4096, p.b1[2], xs, lane, wl0, fused);
    do_branch<9, 4>(frag + (size_t)88 * 512, frag + 81920 + (size_t)3 * 4096, p.b1[3], xs, lane, wl0, fused);

#ifndef HAVE_MFMA16
    asm volatile("s_nop 7\ns_nop 7");   // MFMA->VALU hazard guard for asm path
#endif

    // write output: out[b][l][c] = fused[c][l], fp32, channel-contiguous float4
    int col = lane & 15;
    #pragma unroll
    for (int mt = 0; mt < 4; mt++) {
        #pragma unroll
        for (int nt = 0; nt < 4; nt++) {
            int l = t0 + wl0 + nt * 16 + col;
            *(f32x4*)&out[((size_t)b * Ln + l) * 64 + mt * 16 + kg * 4] = fused[mt][nt];
        }
    }
}

extern "C" void kernel_launch(void* const* d_in, const int* in_sizes, int n_in,
                              void* d_out, int out_size, void* d_ws, size_t ws_size,
                              hipStream_t stream) {
    Ptrs p;
    p.x  = (const float*)d_in[0];
    p.rw = (const float*)d_in[1];
    for (int i = 0; i < 4; i++) {
        p.w1[i] = (const float*)d_in[2 + 4 * i];
        p.b1[i] = (const float*)d_in[3 + 4 * i];
        p.w2[i] = (const float*)d_in[4 + 4 * i];
        p.b2[i] = (const float*)d_in[5 + 4 * i];
    }
    float* hdr = (float*)d_ws;
    unsigned short* frag = (unsigned short*)((char*)d_ws + 512);

    hipLaunchKernelGGL(prep_kernel, dim3(96), dim3(256), 0, stream, p, frag, hdr);
    hipLaunchKernelGGL(wavelet_main, dim3(Bn * (Ln / NT)), dim3(256), 0, stream, p, frag, hdr,
                       (float*)d_out);
}